// Round 15
// baseline (245.355 us; speedup 1.0000x reference)
//
#include <hip/hip_runtime.h>
#include <hip/hip_bf16.h>

typedef _Float16 half4_t __attribute__((ext_vector_type(4)));
typedef _Float16 half8_t __attribute__((ext_vector_type(8)));
typedef float    float4_t __attribute__((ext_vector_type(4)));

#define MFMA32(a, b, c) __builtin_amdgcn_mfma_f32_16x16x32_f16((a), (b), (c), 0, 0, 0)

constexpr int  Bb  = 1024;
constexpr long CTX = (long)Bb * 64 * 512;      // attn offset in d_out
constexpr int  SQP = 520;                      // sQ (q / V^T) row stride (halves)
constexpr int  SMP = 520;                      // sM row stride (halves)
constexpr int  AP  = 72;                       // sAttn row stride (halves)
constexpr long V2OFF = 524288;                 // V2 offset into ws (halves)
constexpr long Q2OFF = V2OFF + (long)Bb * 32768;   // q2 offset (halves)

// ---- pre-pass: pack W (f32 [e][f]) into fragment layout fp16 ----
// W2[(E*16+c)*512 + lane*8 + j] = W[E*16+(lane&15)][c*32+(lane>>4)*8+j]
__global__ void w_pack(const float* __restrict__ W, _Float16* __restrict__ W2) {
    const int t = blockIdx.x * 256 + threadIdx.x;      // 32768 threads
    const int lane = t & 63, grp = t >> 6;             // grp 0..511
    const int E = grp >> 4, c = grp & 15;
    const int r16 = lane & 15, q = lane >> 4;
    const float* src = W + (long)(E * 16 + r16) * 512 + c * 32 + q * 8;
    float4_t x = *(const float4_t*)(src);
    float4_t y = *(const float4_t*)(src + 4);
    half8_t h;
    h[0]=(_Float16)x[0]; h[1]=(_Float16)x[1]; h[2]=(_Float16)x[2]; h[3]=(_Float16)x[3];
    h[4]=(_Float16)y[0]; h[5]=(_Float16)y[1]; h[6]=(_Float16)y[2]; h[7]=(_Float16)y[3];
    *(half8_t*)(W2 + (long)t * 8) = h;
}

// ---- kernel V: stage q->LDS; emit q2 (ctx B-frag layout); V^T = q*W^T -> V2 ----
__global__ __launch_bounds__(512, 2)
void ovo_v(const float* __restrict__ qm, const _Float16* __restrict__ W2,
           _Float16* __restrict__ V2, _Float16* __restrict__ Q2)
{
    __shared__ __align__(16) _Float16 sQ[64 * SQP];   // q fp16, then V^T; 66.6 KB

    const int t = threadIdx.x, lane = t & 63, w = t >> 6;
    const int r16 = lane & 15, q = lane >> 4;
    const long base = (long)blockIdx.x * 64 * 512;
    const float4_t zf4 = {0.f, 0.f, 0.f, 0.f};

    // stage q fp16, flat-linear
    {
        const long qb = base + (long)t * 4;
        #pragma unroll
        for (int k = 0; k < 16; ++k) {
            float4_t v = *(const float4_t*)(qm + qb + (long)k * 2048);
            half4_t h;
            h[0]=(_Float16)v[0]; h[1]=(_Float16)v[1]; h[2]=(_Float16)v[2]; h[3]=(_Float16)v[3];
            *(half4_t*)(&sQ[(k * 4 + (t >> 7)) * SQP + (t & 127) * 4]) = h;
        }
    }
    __syncthreads();

    // q2 write (transposed-fragment layout for context B operand)
    {
        _Float16* q2dst = Q2 + (long)blockIdx.x * 32768;
        #pragma unroll
        for (int i = 0; i < 8; ++i) {
            const int grp = w * 8 + i;          // et*2 + cc
            const int et = grp >> 1, cc = grp & 1;
            half8_t hv;
            #pragma unroll
            for (int j = 0; j < 8; ++j)
                hv[j] = sQ[(cc * 32 + q * 8 + j) * SQP + et * 16 + r16];
            *(half8_t*)(q2dst + (long)grp * 512 + lane * 8) = hv;
        }
    }

    // V^T[g][e] = sum_f q[g,f]*W[e,f]; wave w owns e-slice [64w, 64w+64)
    float4_t vacc[4][4];   // [g2][et]
    #pragma unroll
    for (int i = 0; i < 4; ++i)
        #pragma unroll
        for (int j = 0; j < 4; ++j) vacc[i][j] = zf4;

    #pragma unroll
    for (int c = 0; c < 16; ++c) {
        half8_t Aq[4], Bw[4];
        #pragma unroll
        for (int g2 = 0; g2 < 4; ++g2)
            Aq[g2] = *(const half8_t*)(&sQ[(g2 * 16 + r16) * SQP + c * 32 + q * 8]);
        #pragma unroll
        for (int et = 0; et < 4; ++et)
            Bw[et] = *(const half8_t*)(W2 + (long)((w * 4 + et) * 16 + c) * 512 + lane * 8);
        #pragma unroll
        for (int g2 = 0; g2 < 4; ++g2)
            #pragma unroll
            for (int et = 0; et < 4; ++et)
                vacc[g2][et] = MFMA32(Aq[g2], Bw[et], vacc[g2][et]);
    }
    __syncthreads();                       // q dead (q2 written, GEMM done)

    #pragma unroll
    for (int g2 = 0; g2 < 4; ++g2)
        #pragma unroll
        for (int et = 0; et < 4; ++et)
            #pragma unroll
            for (int r = 0; r < 4; ++r)
                sQ[(g2 * 16 + q * 4 + r) * SQP + w * 64 + et * 16 + r16] =
                    (_Float16)vacc[g2][et][r];
    __syncthreads();

    _Float16* vdst = V2 + (long)blockIdx.x * 32768;
    #pragma unroll
    for (int i = 0; i < 8; ++i) {
        const int grp = w * 8 + i;              // 0..63 = gt*16 + cc
        const int gt = grp >> 4, cc = grp & 15;
        half8_t hv = *(const half8_t*)(&sQ[(gt * 16 + r16) * SQP + cc * 32 + q * 8]);
        *(half8_t*)(vdst + (long)grp * 512 + lane * 8) = hv;
    }
}

// ---- kernel SC: o-stage -> mean -> score -> softmax -> attn AND context ----
// LDS overlay: sPool holds sM (fp16, during stage+score) then sRed (f32 partials).
__global__ __launch_bounds__(256, 8)
void ovo_sc(const float* __restrict__ o1, const float* __restrict__ o2,
            const float* __restrict__ o3, const _Float16* __restrict__ V2,
            const _Float16* __restrict__ Q2, float* __restrict__ out)
{
    __shared__ __align__(16) float sPool[4352];       // 17408 B: sM | sRed overlay
    __shared__ __align__(16) _Float16 sAttn[16 * AP]; // 2.3 KB attn fp16

    _Float16* sM = reinterpret_cast<_Float16*>(sPool);            // 16*SMP halves = 16640 B
    float (*sRed)[16 * 68] = reinterpret_cast<float(*)[16 * 68]>(sPool);

    const int t = threadIdx.x, lane = t & 63, w = t >> 6;   // 4 waves = 4 e-slices
    const int r16 = lane & 15, q = lane >> 4;

    // XCD-chunked swizzle (V2/q2 L2 reuse: 4 hq-blocks of a batch co-resident)
    const int l = blockIdx.x;
    const int xcd = l & 7, m = l >> 3;
    const int b  = xcd * 128 + (m >> 2);
    const int hq = m & 3;

    const long cbase = (long)b * 32768 + (long)hq * 8192;   // floats
    const _Float16* vb  = V2 + (long)b * 32768;
    const _Float16* qb2 = Q2 + (long)b * 32768;
    const float4_t zf4 = {0.f, 0.f, 0.f, 0.f};

    // ---- linear stage: 1 KB-contiguous wave reads ----
    const float* p1 = o1 + cbase + t * 4;
    const float* p2 = o2 + cbase + t * 4;
    const float* p3 = o3 + cbase + t * 4;
    const int srow0 = t >> 7, scol = (t & 127) * 4;

    {
        float4_t A1[4], A2[4], A3[4];
        #pragma unroll
        for (int i = 0; i < 4; ++i) A1[i] = *(const float4_t*)(p1 + i * 1024);
        #pragma unroll
        for (int i = 0; i < 4; ++i) A2[i] = *(const float4_t*)(p2 + i * 1024);
        #pragma unroll
        for (int i = 0; i < 4; ++i) A3[i] = *(const float4_t*)(p3 + i * 1024);
        #pragma unroll
        for (int i = 0; i < 4; ++i) {
            float4_t mv = (A1[i] + A2[i] + A3[i]) * (1.0f / 3.0f);
            half4_t h;
            h[0]=(_Float16)mv[0]; h[1]=(_Float16)mv[1]; h[2]=(_Float16)mv[2]; h[3]=(_Float16)mv[3];
            *(half4_t*)(&sM[(i * 2 + srow0) * SMP + scol]) = h;
        }
        float4_t B1[4], B2[4], B3[4];
        #pragma unroll
        for (int i = 0; i < 4; ++i) B1[i] = *(const float4_t*)(p1 + (i + 4) * 1024);
        #pragma unroll
        for (int i = 0; i < 4; ++i) B2[i] = *(const float4_t*)(p2 + (i + 4) * 1024);
        #pragma unroll
        for (int i = 0; i < 4; ++i) B3[i] = *(const float4_t*)(p3 + (i + 4) * 1024);
        #pragma unroll
        for (int i = 0; i < 4; ++i) {
            float4_t mv = (B1[i] + B2[i] + B3[i]) * (1.0f / 3.0f);
            half4_t h;
            h[0]=(_Float16)mv[0]; h[1]=(_Float16)mv[1]; h[2]=(_Float16)mv[2]; h[3]=(_Float16)mv[3];
            *(half4_t*)(&sM[((i + 4) * 2 + srow0) * SMP + scol]) = h;
        }
    }
    __syncthreads();

    // ---- score: wave w owns e-slice [w*128, w*128+128) ----
    float4_t acc0 = zf4, acc1 = zf4, acc2 = zf4, acc3 = zf4;

    #define SCOMP(c) do { \
        half8_t af = *(const half8_t*)(&sM[r16 * SMP + w * 128 + (c) * 32 + q * 8]); \
        half8_t bf0 = *(const half8_t*)(vb + (long)( 0 + w * 4 + (c)) * 512 + lane * 8); \
        half8_t bf1 = *(const half8_t*)(vb + (long)(16 + w * 4 + (c)) * 512 + lane * 8); \
        half8_t bf2 = *(const half8_t*)(vb + (long)(32 + w * 4 + (c)) * 512 + lane * 8); \
        half8_t bf3 = *(const half8_t*)(vb + (long)(48 + w * 4 + (c)) * 512 + lane * 8); \
        acc0 = MFMA32(af, bf0, acc0); \
        acc1 = MFMA32(af, bf1, acc1); \
        acc2 = MFMA32(af, bf2, acc2); \
        acc3 = MFMA32(af, bf3, acc3); \
    } while (0)

    SCOMP(0); SCOMP(1); SCOMP(2); SCOMP(3);
    __syncthreads();                       // sM reads done -> sRed may overwrite

    // partials: sRed[w][h*68 + g], h=(q*4+r), g=gt*16+r16
    #pragma unroll
    for (int r = 0; r < 4; ++r) {
        sRed[w][(q * 4 + r) * 68 +  0 + r16] = acc0[r];
        sRed[w][(q * 4 + r) * 68 + 16 + r16] = acc1[r];
        sRed[w][(q * 4 + r) * 68 + 32 + r16] = acc2[r];
        sRed[w][(q * 4 + r) * 68 + 48 + r16] = acc3[r];
    }
    __syncthreads();
    if (w == 0) {
        for (int i = 0; i < 17; ++i)
            sRed[0][lane + i * 64] += sRed[2][lane + i * 64];
    }
    if (w == 1) {
        for (int i = 0; i < 17; ++i)
            sRed[1][lane + i * 64] += sRed[3][lane + i * 64];
    }
    __syncthreads();
    if (w == 0) {
        for (int i = 0; i < 17; ++i)
            sRed[0][lane + i * 64] += sRed[1][lane + i * 64];
    }
    __syncthreads();

    // softmax over g (wave 0: 16 rows, 4 lanes/row); attn -> out + sAttn(fp16)
    if (w == 0) {
        const float* srow = &sRed[0][r16 * 68 + q * 16];
        float v[16];
        float mx = -1e30f;
        #pragma unroll
        for (int i = 0; i < 16; ++i) { v[i] = srow[i]; mx = fmaxf(mx, v[i]); }
        mx = fmaxf(mx, __shfl_xor(mx, 16));
        mx = fmaxf(mx, __shfl_xor(mx, 32));
        float sum = 0.f;
        #pragma unroll
        for (int i = 0; i < 16; ++i) { v[i] = __expf(v[i] - mx); sum += v[i]; }
        sum += __shfl_xor(sum, 16);
        sum += __shfl_xor(sum, 32);
        const float inv = 1.0f / sum;
        float* aout = out + CTX + ((long)b * 64 + hq * 16 + r16) * 64 + q * 16;
        #pragma unroll
        for (int i = 0; i < 16; ++i) {
            float a = v[i] * inv;
            aout[i] = a;
            sAttn[r16 * AP + q * 16 + i] = (_Float16)a;
        }
    }
    __syncthreads();

    // ---- context: ctx[h][e] = attn[h][:] @ q ; wave w owns e-tiles [w*8, w*8+8) ----
    {
        half8_t a0 = *(const half8_t*)(&sAttn[r16 * AP + q * 8]);        // k-chunk 0
        half8_t a1 = *(const half8_t*)(&sAttn[r16 * AP + 32 + q * 8]);   // k-chunk 1
        #pragma unroll
        for (int i = 0; i < 8; ++i) {
            const int et = w * 8 + i;
            half8_t b0 = *(const half8_t*)(qb2 + (long)(et * 2 + 0) * 512 + lane * 8);
            half8_t b1 = *(const half8_t*)(qb2 + (long)(et * 2 + 1) * 512 + lane * 8);
            float4_t acc = MFMA32(a0, b0, zf4);
            acc = MFMA32(a1, b1, acc);
            #pragma unroll
            for (int r = 0; r < 4; ++r)
                out[((long)b * 64 + hq * 16 + q * 4 + r) * 512 + et * 16 + r16] = acc[r];
        }
    }
}

extern "C" void kernel_launch(void* const* d_in, const int* in_sizes, int n_in,
                              void* d_out, int out_size, void* d_ws, size_t ws_size,
                              hipStream_t stream) {
    const float* o1 = (const float*)d_in[0];
    const float* o2 = (const float*)d_in[1];
    const float* o3 = (const float*)d_in[2];
    const float* qm = (const float*)d_in[3];
    const float* W  = (const float*)d_in[4];
    float* out = (float*)d_out;
    _Float16* W2 = (_Float16*)d_ws;                 // 1 MB  fragment-layout fp16 W
    _Float16* V2 = (_Float16*)d_ws + V2OFF;         // 67 MB fragment-layout fp16 V
    _Float16* Q2 = (_Float16*)d_ws + Q2OFF;         // 67 MB ctx-B-frag fp16 q

    w_pack<<<dim3(128), dim3(256), 0, stream>>>(W, W2);
    ovo_v<<<dim3(Bb), dim3(512), 0, stream>>>(qm, W2, V2, Q2);
    ovo_sc<<<dim3(Bb * 4), dim3(256), 0, stream>>>(o1, o2, o3, V2, Q2, out);
}